// Round 4
// baseline (8504.018 us; speedup 1.0000x reference)
//
#include <hip/hip_runtime.h>

// ---------------- problem constants ----------------
#define T_STEPS 128
#define N_B     512
#define D_IN    1024
#define H_DIM   1024
#define G_DIM   3072        // 3*H
#define CHUNK   8           // timesteps per xp-GEMM chunk / persistent launch
#define NCHUNK  16
#define M_CHUNK (CHUNK * N_B)   // 4096 rows per xp-GEMM chunk

typedef short          s8v  __attribute__((ext_vector_type(8)));   // 8 bf16 (4 VGPR)
typedef float          f4v  __attribute__((ext_vector_type(4)));
typedef unsigned short u4v  __attribute__((ext_vector_type(4)));

__device__ __forceinline__ unsigned short f2bf(float f) {
  union { float f; unsigned u; } v; v.f = f;
  unsigned r = v.u + 0x7FFFu + ((v.u >> 16) & 1u);   // RNE
  return (unsigned short)(r >> 16);
}
__device__ __forceinline__ float bf2f(unsigned short h) {
  union { unsigned u; float f; } v; v.u = ((unsigned)h) << 16;
  return v.f;
}
__device__ __forceinline__ void async16(const void* g, void* l) {
  __builtin_amdgcn_global_load_lds(
      (const __attribute__((address_space(1))) unsigned*)g,
      (__attribute__((address_space(3))) unsigned*)l, 16, 0, 0);
}
__device__ __forceinline__ float sigmoidf_(float x) { return 1.f / (1.f + __expf(-x)); }
__device__ __forceinline__ float tanhf_(float x)    { return 1.f - 2.f / (1.f + __expf(2.f * x)); }

// ---------------- f32 -> bf16 conversion (vectorized, grid-stride) ----------------
__global__ void cvt_bf16(const float* __restrict__ in, unsigned short* __restrict__ out, long n4) {
  long i = (long)blockIdx.x * blockDim.x + threadIdx.x;
  long stride = (long)gridDim.x * blockDim.x;
  for (; i < n4; i += stride) {
    f4v v = *(const f4v*)(in + i * 4);
    u4v o;
    #pragma unroll
    for (int e = 0; e < 4; ++e) o[e] = f2bf(v[e]);
    *(u4v*)(out + i * 4) = o;
  }
}

// ---------------- reset[t] = (t==0) || any(m[t,:]==1.0) ----------------
__global__ void reset_kernel(const float* __restrict__ masks, int* __restrict__ reset) {
  const int t = blockIdx.x;
  __shared__ int flag;
  if (threadIdx.x == 0) flag = (t == 0) ? 1 : 0;
  __syncthreads();
  if (t > 0 && masks[(size_t)t * N_B + threadIdx.x] == 1.0f) flag = 1;  // benign same-value race
  __syncthreads();
  if (threadIdx.x == 0) reset[t] = flag;
}

// ---------------- xp chunk GEMM: C[m][g] = sum_k A[m][k]*B[g][k] + bias[g] ----------------
__global__ __launch_bounds__(256) void gemm_xp(const unsigned short* __restrict__ A,
                                               const unsigned short* __restrict__ B,
                                               const float* __restrict__ bias,
                                               unsigned short* __restrict__ C) {
  const int m0 = blockIdx.y * 128, g0 = blockIdx.x * 128;
  const int tid = threadIdx.x, wv = tid >> 6, l = tid & 63;
  const int l15 = l & 15, l4 = l >> 4;
  const int wr = wv >> 1, wc = wv & 1;
  __shared__ unsigned short As[128 * 64], Bs[128 * 64];

  f4v zero4 = {0.f, 0.f, 0.f, 0.f};
  f4v acc[4][4];
  #pragma unroll
  for (int i = 0; i < 4; ++i)
    #pragma unroll
    for (int j = 0; j < 4; ++j) acc[i][j] = zero4;

  const int srow = l >> 3;
  const int selem = (l & 7) * 8;

  for (int kt = 0; kt < 1024; kt += 64) {
    #pragma unroll
    for (int cc = 0; cc < 4; ++cc) {
      int s = wv * 4 + cc;
      int row = s * 8 + srow;
      async16(A + (size_t)(m0 + row) * 1024 + kt + selem, &As[s * 512]);
      async16(B + (size_t)(g0 + row) * 1024 + kt + selem, &Bs[s * 512]);
    }
    __syncthreads();
    #pragma unroll
    for (int ks = 0; ks < 2; ++ks) {
      s8v a[4], b[4];
      #pragma unroll
      for (int i = 0; i < 4; ++i) {
        a[i] = *(const s8v*)&As[(wr * 64 + i * 16 + l15) * 64 + ks * 32 + l4 * 8];
        b[i] = *(const s8v*)&Bs[(wc * 64 + i * 16 + l15) * 64 + ks * 32 + l4 * 8];
      }
      #pragma unroll
      for (int i = 0; i < 4; ++i)
        #pragma unroll
        for (int j = 0; j < 4; ++j)
          acc[i][j] = __builtin_amdgcn_mfma_f32_16x16x32_bf16(a[i], b[j], acc[i][j], 0, 0, 0);
    }
    __syncthreads();
  }
  #pragma unroll
  for (int j = 0; j < 4; ++j) {
    int gcol = g0 + wc * 64 + j * 16 + l15;
    float bv = bias[gcol];
    #pragma unroll
    for (int i = 0; i < 4; ++i) {
      int mrow = m0 + wr * 64 + i * 16 + l4 * 4;
      #pragma unroll
      for (int r = 0; r < 4; ++r)
        C[(size_t)(mrow + r) * G_DIM + gcol] = f2bf(acc[i][j][r] + bv);
    }
  }
}

// ---------------- persistent GRU recurrence over CHUNK steps (plain launch) ----------------
// 256 blocks: g = bid&7 (n-group of 64 rows, pinned to XCD g), c = bid>>3 (32 j-chunks of 32).
// W_hh held in registers as MFMA B-fragments (K split across 4 waves: 192 VGPR/lane);
// per-wave partial C reduced via LDS atomicAdd. h f32 state lives in registers across steps.
// Inter-block sync: 32-block group spin barrier (device-scope atomics, XCD-local).
__global__ __launch_bounds__(256, 1) void rnn_chunk(
    const unsigned short* __restrict__ Whh,   // [3072][1024] bf16
    const unsigned short* __restrict__ xp,    // [CHUNK][512][3072] bf16 (+b_ih)
    const float* __restrict__ masks,          // [T*N]
    const int* __restrict__ reset,            // [T]
    const float* __restrict__ bhh,            // [3072]
    const float* __restrict__ hxs,            // [512][1024] initial h (f32)
    unsigned short* hbuf,                     // [2][512][1024] bf16 state
    float* y,                                 // [T*N][1024] (d_out)
    float* hlast,                             // [512][1024]  (d_out tail)
    unsigned* bar,                            // [8] group counters (this launch's slot)
    int t0) {
  const int tid = threadIdx.x;
  const int bid = blockIdx.x;
  const int g = bid & 7, c = bid >> 3;
  const int n0 = g * 64, j0 = c * 32;
  const int w = tid >> 6, l = tid & 63;
  const int l15 = l & 15, l4 = l >> 4;
  const int kbase = w * 256;                   // wave w owns k in [256w, 256w+256)
  const size_t NH = (size_t)N_B * H_DIM;

  __shared__ float hp[96 * 65];                // hp partials, [col 0..95][row 0..63] padded

  // ---- preload W_hh B-fragments (once per launch): ct 0..5, ks 0..7 ----
  s8v Bf[6][8];
  #pragma unroll
  for (int ct = 0; ct < 6; ++ct) {
    int row = (ct >> 1) * H_DIM + j0 + (ct & 1) * 16 + l15;   // W row = gate*1024 + j
    #pragma unroll
    for (int ks = 0; ks < 8; ++ks)
      Bf[ct][ks] = *(const s8v*)(Whh + (size_t)row * 1024 + kbase + ks * 32 + l4 * 8);
  }

  // ---- gate-phase mapping: thread (jl, ngrp) owns 8 n-rows at column j0+jl ----
  const int jl = tid & 31;
  const int ngrp = tid >> 5;                   // 0..7
  const float br = bhh[0 * H_DIM + j0 + jl];
  const float bz = bhh[1 * H_DIM + j0 + jl];
  const float bn = bhh[2 * H_DIM + j0 + jl];

  // ---- f32 h state in registers ----
  float hreg[8];
  {
    const float* hsrc = (t0 == 0) ? hxs : (y + (size_t)(t0 - 1) * NH);
    #pragma unroll
    for (int p = 0; p < 8; ++p)
      hreg[p] = hsrc[(size_t)(n0 + ngrp * 8 + p) * H_DIM + j0 + jl];
  }

  f4v zero4 = {0.f, 0.f, 0.f, 0.f};
  s8v zer8 = {0, 0, 0, 0, 0, 0, 0, 0};

  for (int ls = 0; ls < CHUNK; ++ls) {
    const int t = t0 + ls;
    const unsigned short* hread = hbuf + (size_t)(t & 1) * NH;
    unsigned short* hwrite = hbuf + (size_t)((t & 1) ^ 1) * NH;
    const int rst = reset[t];

    // 1. clear partial accumulator
    for (int i = tid; i < 96 * 65; i += 256) hp[i] = 0.f;
    __syncthreads();

    // 2. MFMA: partial hp over this wave's K range
    f4v acc[4][6];
    #pragma unroll
    for (int rf = 0; rf < 4; ++rf)
      #pragma unroll
      for (int ct = 0; ct < 6; ++ct) acc[rf][ct] = zero4;

    #pragma unroll
    for (int rf = 0; rf < 4; ++rf) {
      int nl = rf * 16 + l15;
      float mval = masks[(size_t)t * N_B + n0 + nl];
      bool zo = rst && (mval == 0.0f);
      const unsigned short* arow = hread + (size_t)(n0 + nl) * H_DIM + kbase;
      s8v a[8];
      #pragma unroll
      for (int ks = 0; ks < 8; ++ks) {
        a[ks] = *(const s8v*)(arow + ks * 32 + l4 * 8);
        a[ks] = zo ? zer8 : a[ks];
      }
      #pragma unroll
      for (int ks = 0; ks < 8; ++ks)
        #pragma unroll
        for (int ct = 0; ct < 6; ++ct)
          acc[rf][ct] = __builtin_amdgcn_mfma_f32_16x16x32_bf16(a[ks], Bf[ct][ks], acc[rf][ct], 0, 0, 0);
    }

    // 3. reduce partials into LDS (4 waves hit same addrs -> atomic)
    #pragma unroll
    for (int rf = 0; rf < 4; ++rf)
      #pragma unroll
      for (int ct = 0; ct < 6; ++ct) {
        int col = ct * 16 + l15;
        int rowb = rf * 16 + l4 * 4;
        #pragma unroll
        for (int r = 0; r < 4; ++r)
          atomicAdd(&hp[col * 65 + rowb + r], acc[rf][ct][r]);
      }
    __syncthreads();

    // 4. gates + state update + outputs
    const unsigned short* xpt = xp + (size_t)ls * N_B * G_DIM;
    #pragma unroll
    for (int p = 0; p < 8; ++p) {
      const int nl = ngrp * 8 + p;
      const int n = n0 + nl;
      const float m = masks[(size_t)t * N_B + n];
      float hprev = hreg[p];
      if (rst && m == 0.0f) hprev = 0.0f;
      const float hr = hp[(0 * 32 + jl) * 65 + nl] + br;
      const float hz = hp[(1 * 32 + jl) * 65 + nl] + bz;
      const float hn = hp[(2 * 32 + jl) * 65 + nl] + bn;
      const size_t xo = (size_t)n * G_DIM + j0 + jl;
      const float xr = bf2f(xpt[xo]);
      const float xz = bf2f(xpt[xo + H_DIM]);
      const float xn = bf2f(xpt[xo + 2 * H_DIM]);
      const float rg = sigmoidf_(xr + hr);
      const float zg = sigmoidf_(xz + hz);
      const float ng = tanhf_(xn + rg * hn);
      const float hnew = (1.f - zg) * ng + zg * hprev;
      hreg[p] = hnew;
      const size_t gidx = (size_t)n * H_DIM + j0 + jl;
      y[(size_t)t * NH + gidx] = hnew;
      hwrite[gidx] = f2bf(hnew);
      if (t == T_STEPS - 1) hlast[gidx] = hnew;
    }

    // 5. group barrier (32 blocks, same XCD), release/acquire
    __syncthreads();                            // drains vmcnt before arrival
    if (tid == 0) {
      __hip_atomic_fetch_add(&bar[g], 1u, __ATOMIC_RELEASE, __HIP_MEMORY_SCOPE_AGENT);
      const unsigned tgt = 32u * (unsigned)(ls + 1);
      while (__hip_atomic_load(&bar[g], __ATOMIC_ACQUIRE, __HIP_MEMORY_SCOPE_AGENT) < tgt)
        __builtin_amdgcn_s_sleep(4);
    }
    __syncthreads();
    __builtin_amdgcn_fence(__ATOMIC_ACQUIRE, "agent");   // invalidate L1 before next h reads
  }
}

// ---------------- final LayerNorm over y rows (in place) ----------------
__global__ __launch_bounds__(256) void ln_kernel(float* __restrict__ y,
                                                 const float* __restrict__ gamma,
                                                 const float* __restrict__ beta) {
  const size_t row = blockIdx.x;
  float* p = y + row * (size_t)H_DIM;
  const int tid = threadIdx.x;
  f4v v = *(const f4v*)(p + tid * 4);
  float s = v[0] + v[1] + v[2] + v[3];
  float q = v[0] * v[0] + v[1] * v[1] + v[2] * v[2] + v[3] * v[3];
  #pragma unroll
  for (int off = 32; off > 0; off >>= 1) {
    s += __shfl_down(s, off);
    q += __shfl_down(q, off);
  }
  __shared__ float sb[8];
  const int wid = tid >> 6, lid = tid & 63;
  if (lid == 0) { sb[wid] = s; sb[4 + wid] = q; }
  __syncthreads();
  float S = sb[0] + sb[1] + sb[2] + sb[3];
  float Q = sb[4] + sb[5] + sb[6] + sb[7];
  float mean = S * (1.f / H_DIM);
  float var = Q * (1.f / H_DIM) - mean * mean;
  float inv = rsqrtf(var + 1e-5f);
  f4v g4 = *(const f4v*)(gamma + tid * 4);
  f4v b4 = *(const f4v*)(beta + tid * 4);
  f4v o;
  #pragma unroll
  for (int e = 0; e < 4; ++e) o[e] = (v[e] - mean) * inv * g4[e] + b4[e];
  *(f4v*)(p + tid * 4) = o;
}

// ---------------- host ----------------
extern "C" void kernel_launch(void* const* d_in, const int* in_sizes, int n_in,
                              void* d_out, int out_size, void* d_ws, size_t ws_size,
                              hipStream_t stream) {
  const float* x     = (const float*)d_in[0];
  const float* hxs   = (const float*)d_in[1];
  const float* masks = (const float*)d_in[2];
  const float* W_ih  = (const float*)d_in[3];
  const float* W_hh  = (const float*)d_in[4];
  const float* b_ih  = (const float*)d_in[5];
  const float* b_hh  = (const float*)d_in[6];
  const float* gamma = (const float*)d_in[7];
  const float* beta  = (const float*)d_in[8];
  float* y = (float*)d_out;                                 // [65536][1024]
  float* hlast = y + (size_t)T_STEPS * N_B * H_DIM;         // [512][1024]

  char* ws = (char*)d_ws;
  unsigned short* Wih_bf = (unsigned short*)ws;  ws += (size_t)G_DIM * D_IN * 2;       // 6.3 MB
  unsigned short* Whh_bf = (unsigned short*)ws;  ws += (size_t)G_DIM * H_DIM * 2;      // 6.3 MB
  unsigned short* xc_bf  = (unsigned short*)ws;  ws += (size_t)M_CHUNK * D_IN * 2;     // 8.4 MB
  unsigned short* xp_bf  = (unsigned short*)ws;  ws += (size_t)M_CHUNK * G_DIM * 2;    // 25.2 MB
  unsigned short* hbuf   = (unsigned short*)ws;  ws += (size_t)2 * N_B * H_DIM * 2;    // 2.1 MB
  int* reset             = (int*)ws;             ws += 512;
  unsigned* bars         = (unsigned*)ws;        ws += NCHUNK * 8 * sizeof(unsigned);

  hipMemsetAsync(bars, 0, NCHUNK * 8 * sizeof(unsigned), stream);
  cvt_bf16<<<1024, 256, 0, stream>>>(W_ih, Wih_bf, (long)G_DIM * D_IN / 4);
  cvt_bf16<<<1024, 256, 0, stream>>>(W_hh, Whh_bf, (long)G_DIM * H_DIM / 4);
  cvt_bf16<<<512, 256, 0, stream>>>(hxs, hbuf, (long)N_B * H_DIM / 4);   // hbuf[0] = bf16(h0)
  reset_kernel<<<128, 512, 0, stream>>>(masks, reset);

  for (int ck = 0; ck < NCHUNK; ++ck) {
    const float* xck = x + (size_t)ck * M_CHUNK * D_IN;
    cvt_bf16<<<2048, 256, 0, stream>>>(xck, xc_bf, (long)M_CHUNK * D_IN / 4);
    dim3 gg(G_DIM / 128, M_CHUNK / 128);   // (24, 32)
    gemm_xp<<<gg, 256, 0, stream>>>(xc_bf, Wih_bf, b_ih, xp_bf);

    rnn_chunk<<<256, 256, 0, stream>>>(Whh_bf, xp_bf, masks, reset, b_hh,
                                       hxs, hbuf, y, hlast, bars + ck * 8, ck * CHUNK);
  }

  ln_kernel<<<T_STEPS * N_B, 256, 0, stream>>>(y, gamma, beta);
}

// Round 5
// 5184.182 us; speedup vs baseline: 1.6404x; 1.6404x over previous
//
#include <hip/hip_runtime.h>

// ---------------- problem constants ----------------
#define T_STEPS 128
#define N_B     512
#define D_IN    1024
#define H_DIM   1024
#define G_DIM   3072        // 3*H
#define CHUNK   8           // timesteps per xp-GEMM chunk / persistent launch
#define NCHUNK  16
#define M_CHUNK (CHUNK * N_B)   // 4096 rows per xp-GEMM chunk

typedef short          s8v  __attribute__((ext_vector_type(8)));   // 8 bf16 (4 VGPR)
typedef float          f4v  __attribute__((ext_vector_type(4)));
typedef unsigned short u4v  __attribute__((ext_vector_type(4)));

__device__ __forceinline__ unsigned short f2bf(float f) {
  union { float f; unsigned u; } v; v.f = f;
  unsigned r = v.u + 0x7FFFu + ((v.u >> 16) & 1u);   // RNE
  return (unsigned short)(r >> 16);
}
__device__ __forceinline__ float bf2f(unsigned short h) {
  union { unsigned u; float f; } v; v.u = ((unsigned)h) << 16;
  return v.f;
}
__device__ __forceinline__ void async16(const void* g, void* l) {
  __builtin_amdgcn_global_load_lds(
      (const __attribute__((address_space(1))) unsigned*)g,
      (__attribute__((address_space(3))) unsigned*)l, 16, 0, 0);
}
__device__ __forceinline__ float sigmoidf_(float x) { return 1.f / (1.f + __expf(-x)); }
__device__ __forceinline__ float tanhf_(float x)    { return 1.f - 2.f / (1.f + __expf(2.f * x)); }

// ---------------- f32 -> bf16 conversion (vectorized, grid-stride) ----------------
__global__ void cvt_bf16(const float* __restrict__ in, unsigned short* __restrict__ out, long n4) {
  long i = (long)blockIdx.x * blockDim.x + threadIdx.x;
  long stride = (long)gridDim.x * blockDim.x;
  for (; i < n4; i += stride) {
    f4v v = *(const f4v*)(in + i * 4);
    u4v o;
    #pragma unroll
    for (int e = 0; e < 4; ++e) o[e] = f2bf(v[e]);
    *(u4v*)(out + i * 4) = o;
  }
}

// ---------------- reset[t] = (t==0) || any(m[t,:]==1.0) ----------------
__global__ void reset_kernel(const float* __restrict__ masks, int* __restrict__ reset) {
  const int t = blockIdx.x;
  __shared__ int flag;
  if (threadIdx.x == 0) flag = (t == 0) ? 1 : 0;
  __syncthreads();
  if (t > 0 && masks[(size_t)t * N_B + threadIdx.x] == 1.0f) flag = 1;  // benign same-value race
  __syncthreads();
  if (threadIdx.x == 0) reset[t] = flag;
}

// ---------------- xp chunk GEMM: C[m][g] = sum_k A[m][k]*B[g][k] + bias[g] ----------------
__global__ __launch_bounds__(256) void gemm_xp(const unsigned short* __restrict__ A,
                                               const unsigned short* __restrict__ B,
                                               const float* __restrict__ bias,
                                               unsigned short* __restrict__ C) {
  const int m0 = blockIdx.y * 128, g0 = blockIdx.x * 128;
  const int tid = threadIdx.x, wv = tid >> 6, l = tid & 63;
  const int l15 = l & 15, l4 = l >> 4;
  const int wr = wv >> 1, wc = wv & 1;
  __shared__ unsigned short As[128 * 64], Bs[128 * 64];

  f4v zero4 = {0.f, 0.f, 0.f, 0.f};
  f4v acc[4][4];
  #pragma unroll
  for (int i = 0; i < 4; ++i)
    #pragma unroll
    for (int j = 0; j < 4; ++j) acc[i][j] = zero4;

  const int srow = l >> 3;
  const int selem = (l & 7) * 8;

  for (int kt = 0; kt < 1024; kt += 64) {
    #pragma unroll
    for (int cc = 0; cc < 4; ++cc) {
      int s = wv * 4 + cc;
      int row = s * 8 + srow;
      async16(A + (size_t)(m0 + row) * 1024 + kt + selem, &As[s * 512]);
      async16(B + (size_t)(g0 + row) * 1024 + kt + selem, &Bs[s * 512]);
    }
    __syncthreads();
    #pragma unroll
    for (int ks = 0; ks < 2; ++ks) {
      s8v a[4], b[4];
      #pragma unroll
      for (int i = 0; i < 4; ++i) {
        a[i] = *(const s8v*)&As[(wr * 64 + i * 16 + l15) * 64 + ks * 32 + l4 * 8];
        b[i] = *(const s8v*)&Bs[(wc * 64 + i * 16 + l15) * 64 + ks * 32 + l4 * 8];
      }
      #pragma unroll
      for (int i = 0; i < 4; ++i)
        #pragma unroll
        for (int j = 0; j < 4; ++j)
          acc[i][j] = __builtin_amdgcn_mfma_f32_16x16x32_bf16(a[i], b[j], acc[i][j], 0, 0, 0);
    }
    __syncthreads();
  }
  #pragma unroll
  for (int j = 0; j < 4; ++j) {
    int gcol = g0 + wc * 64 + j * 16 + l15;
    float bv = bias[gcol];
    #pragma unroll
    for (int i = 0; i < 4; ++i) {
      int mrow = m0 + wr * 64 + i * 16 + l4 * 4;
      #pragma unroll
      for (int r = 0; r < 4; ++r)
        C[(size_t)(mrow + r) * G_DIM + gcol] = f2bf(acc[i][j][r] + bv);
    }
  }
}

// ---------------- persistent GRU recurrence: round-3 compute core + round-4 barrier ----------------
// 256 blocks: g = bid&7 (n-group of 64 rows, pinned to XCD g -> all h traffic XCD-local),
//             c = bid>>3 (32 j-chunks of 32 cols).
// Per step: stage h(64xBK) + W(96xBK) via double-buffered LDS (BK=128, 80KB), full-K per wave
// (no cross-wave reduce), gates in-register, h_prev carried in registers (acc-layout match).
// No W/acc register residency beyond 24 VGPR acc -> no spill (round-4 failure mode).
__global__ __launch_bounds__(256) void rnn_chunk2(
    const unsigned short* __restrict__ Whh,   // [3072][1024] bf16
    const unsigned short* __restrict__ xp,    // [CHUNK][512][3072] bf16 (+b_ih)
    const float* __restrict__ masks,          // [T*N]
    const int* __restrict__ reset,            // [T]
    const float* __restrict__ bhh,            // [3072]
    const float* __restrict__ hxs,            // [512][1024] initial h (f32)
    unsigned short* hbuf,                     // [2][512][1024] bf16 state
    float* y,                                 // [T*N][1024] (d_out)
    float* hlast,                             // [512][1024]  (d_out tail)
    unsigned* bar,                            // [8] group counters (this launch's slot)
    int t0) {
  const int bid = blockIdx.x;
  const int g = bid & 7, c = bid >> 3;
  const int n0 = g * 64, j0 = c * 32;
  const int tid = threadIdx.x, w = tid >> 6, l = tid & 63;
  const int l15 = l & 15, l4 = l >> 4;
  const int wn = w & 1, wj = w >> 1;          // wave -> (n-half of 32, j-half of 16)
  const size_t NH = (size_t)N_B * H_DIM;

  __shared__ unsigned short Hs[2][64 * 128];  // 2 x 16 KB (h slab, swizzled)
  __shared__ unsigned short Ws[2][96 * 128];  // 2 x 24 KB (W slab, swizzled)

  const int lrow4 = l >> 4;                   // staging: lane -> row-within-4
  const int lcb = (l & 15) * 16;              // staging: lane -> 16B col slot
  const int swz_rd = (l15 & 7) << 4;          // read-side row-XOR

  // lane's gate-phase column (fixed for whole kernel)
  const int jj = j0 + wj * 16 + l15;
  const float br = bhh[jj];
  const float bz = bhh[H_DIM + jj];
  const float bn = bhh[2 * H_DIM + jj];

  // h_prev in registers, layout == acc layout: (i,r) -> n = n0+wn*32+i*16+l4*4+r
  float hreg[2][4];
  {
    const float* hsrc = (t0 == 0) ? hxs : (y + (size_t)(t0 - 1) * NH);
    #pragma unroll
    for (int i = 0; i < 2; ++i)
      #pragma unroll
      for (int r = 0; r < 4; ++r)
        hreg[i][r] = hsrc[(size_t)(n0 + wn * 32 + i * 16 + l4 * 4 + r) * H_DIM + jj];
  }

  f4v zero4 = {0.f, 0.f, 0.f, 0.f};
  s8v zer8 = {0, 0, 0, 0, 0, 0, 0, 0};

  for (int ls = 0; ls < CHUNK; ++ls) {
    const int t = t0 + ls;
    const unsigned short* hread = hbuf + (size_t)(t & 1) * NH;
    unsigned short* hwrite = hbuf + (size_t)((t & 1) ^ 1) * NH;
    const int rst = reset[t];

    bool zo[2];
    #pragma unroll
    for (int i = 0; i < 2; ++i) {
      float mv = masks[(size_t)t * N_B + n0 + wn * 32 + i * 16 + l15];
      zo[i] = rst && (mv == 0.0f);
    }

    f4v acc[2][3];
    #pragma unroll
    for (int i = 0; i < 2; ++i)
      #pragma unroll
      for (int g3 = 0; g3 < 3; ++g3) acc[i][g3] = zero4;

    // ---- staging lambdas (wave-uniform LDS dest, per-lane pre-swizzled global src) ----
    auto stageH = [&](int buf, int kt) {
      #pragma unroll
      for (int q = 0; q < 4; ++q) {
        int rb = w * 16 + q * 4;
        int row = rb + lrow4;                                   // 0..63
        int cb = lcb ^ ((row & 7) << 4);                        // byte in 256B row
        async16(hread + (size_t)(n0 + row) * H_DIM + kt * 128 + (cb >> 1),
                &Hs[buf][rb * 128]);
      }
    };
    auto stageW = [&](int buf, int kt) {
      #pragma unroll
      for (int q = 0; q < 6; ++q) {
        int rb = w * 24 + q * 4;
        int row = rb + lrow4;                                   // 0..95
        int gate = row >> 5, jjl = row & 31;
        int cb = lcb ^ ((row & 7) << 4);
        async16(Whh + ((size_t)gate * H_DIM + j0 + jjl) * H_DIM + kt * 128 + (cb >> 1),
                &Ws[buf][rb * 128]);
      }
    };

    stageH(0, 0);
    stageW(0, 0);
    __syncthreads();

    for (int kt = 0; kt < 8; ++kt) {
      const int cur = kt & 1;
      if (kt < 7) { stageH(cur ^ 1, kt + 1); stageW(cur ^ 1, kt + 1); }  // prefetch overlaps MFMA
      const char* hb = (const char*)&Hs[cur][0];
      const char* wb = (const char*)&Ws[cur][0];
      #pragma unroll
      for (int ks = 0; ks < 4; ++ks) {
        const int kbb = (ks * 64 + l4 * 16) ^ swz_rd;
        s8v a[2], b[3];
        #pragma unroll
        for (int i = 0; i < 2; ++i) {
          a[i] = *(const s8v*)(hb + (wn * 32 + i * 16 + l15) * 256 + kbb);
          if (zo[i]) a[i] = zer8;
        }
        #pragma unroll
        for (int g3 = 0; g3 < 3; ++g3)
          b[g3] = *(const s8v*)(wb + (g3 * 32 + wj * 16 + l15) * 256 + kbb);
        #pragma unroll
        for (int i = 0; i < 2; ++i)
          #pragma unroll
          for (int g3 = 0; g3 < 3; ++g3)
            acc[i][g3] = __builtin_amdgcn_mfma_f32_16x16x32_bf16(a[i], b[g3], acc[i][g3], 0, 0, 0);
      }
      __syncthreads();
    }

    // ---- gates fully in-register ----
    const unsigned short* xpt = xp + (size_t)ls * N_B * G_DIM;
    #pragma unroll
    for (int i = 0; i < 2; ++i) {
      #pragma unroll
      for (int r = 0; r < 4; ++r) {
        const int n = n0 + wn * 32 + i * 16 + l4 * 4 + r;
        const float m = masks[(size_t)t * N_B + n];
        float hprev = hreg[i][r];
        if (rst && m == 0.0f) hprev = 0.0f;
        const float hr = acc[i][0][r] + br;
        const float hz = acc[i][1][r] + bz;
        const float hn = acc[i][2][r] + bn;
        const size_t xo = (size_t)n * G_DIM + jj;
        const float xr = bf2f(xpt[xo]);
        const float xz = bf2f(xpt[xo + H_DIM]);
        const float xn = bf2f(xpt[xo + 2 * H_DIM]);
        const float rg = sigmoidf_(xr + hr);
        const float zg = sigmoidf_(xz + hz);
        const float ng = tanhf_(xn + rg * hn);
        const float hnew = (1.f - zg) * ng + zg * hprev;
        hreg[i][r] = hnew;
        const size_t gidx = (size_t)n * H_DIM + jj;
        y[(size_t)t * NH + gidx] = hnew;
        hwrite[gidx] = f2bf(hnew);
        if (t == T_STEPS - 1) hlast[gidx] = hnew;
      }
    }

    // ---- group barrier (32 blocks, same XCD) — round-4 proven pattern ----
    __syncthreads();                            // drains vmcnt for all waves' stores
    if (tid == 0) {
      __hip_atomic_fetch_add(&bar[g], 1u, __ATOMIC_RELEASE, __HIP_MEMORY_SCOPE_AGENT);
      const unsigned tgt = 32u * (unsigned)(ls + 1);
      while (__hip_atomic_load(&bar[g], __ATOMIC_ACQUIRE, __HIP_MEMORY_SCOPE_AGENT) < tgt)
        __builtin_amdgcn_s_sleep(4);
    }
    __syncthreads();
    __builtin_amdgcn_fence(__ATOMIC_ACQUIRE, "agent");   // invalidate caches before next h reads
  }
}

// ---------------- final LayerNorm over y rows (in place) ----------------
__global__ __launch_bounds__(256) void ln_kernel(float* __restrict__ y,
                                                 const float* __restrict__ gamma,
                                                 const float* __restrict__ beta) {
  const size_t row = blockIdx.x;
  float* p = y + row * (size_t)H_DIM;
  const int tid = threadIdx.x;
  f4v v = *(const f4v*)(p + tid * 4);
  float s = v[0] + v[1] + v[2] + v[3];
  float q = v[0] * v[0] + v[1] * v[1] + v[2] * v[2] + v[3] * v[3];
  #pragma unroll
  for (int off = 32; off > 0; off >>= 1) {
    s += __shfl_down(s, off);
    q += __shfl_down(q, off);
  }
  __shared__ float sb[8];
  const int wid = tid >> 6, lid = tid & 63;
  if (lid == 0) { sb[wid] = s; sb[4 + wid] = q; }
  __syncthreads();
  float S = sb[0] + sb[1] + sb[2] + sb[3];
  float Q = sb[4] + sb[5] + sb[6] + sb[7];
  float mean = S * (1.f / H_DIM);
  float var = Q * (1.f / H_DIM) - mean * mean;
  float inv = rsqrtf(var + 1e-5f);
  f4v g4 = *(const f4v*)(gamma + tid * 4);
  f4v b4 = *(const f4v*)(beta + tid * 4);
  f4v o;
  #pragma unroll
  for (int e = 0; e < 4; ++e) o[e] = (v[e] - mean) * inv * g4[e] + b4[e];
  *(f4v*)(p + tid * 4) = o;
}

// ---------------- host ----------------
extern "C" void kernel_launch(void* const* d_in, const int* in_sizes, int n_in,
                              void* d_out, int out_size, void* d_ws, size_t ws_size,
                              hipStream_t stream) {
  const float* x     = (const float*)d_in[0];
  const float* hxs   = (const float*)d_in[1];
  const float* masks = (const float*)d_in[2];
  const float* W_ih  = (const float*)d_in[3];
  const float* W_hh  = (const float*)d_in[4];
  const float* b_ih  = (const float*)d_in[5];
  const float* b_hh  = (const float*)d_in[6];
  const float* gamma = (const float*)d_in[7];
  const float* beta  = (const float*)d_in[8];
  float* y = (float*)d_out;                                 // [65536][1024]
  float* hlast = y + (size_t)T_STEPS * N_B * H_DIM;         // [512][1024]

  char* ws = (char*)d_ws;
  unsigned short* Wih_bf = (unsigned short*)ws;  ws += (size_t)G_DIM * D_IN * 2;       // 6.3 MB
  unsigned short* Whh_bf = (unsigned short*)ws;  ws += (size_t)G_DIM * H_DIM * 2;      // 6.3 MB
  unsigned short* xc_bf  = (unsigned short*)ws;  ws += (size_t)M_CHUNK * D_IN * 2;     // 8.4 MB
  unsigned short* xp_bf  = (unsigned short*)ws;  ws += (size_t)M_CHUNK * G_DIM * 2;    // 25.2 MB
  unsigned short* hbuf   = (unsigned short*)ws;  ws += (size_t)2 * N_B * H_DIM * 2;    // 2.1 MB
  int* reset             = (int*)ws;             ws += 512;
  unsigned* bars         = (unsigned*)ws;        ws += NCHUNK * 8 * sizeof(unsigned);

  hipMemsetAsync(bars, 0, NCHUNK * 8 * sizeof(unsigned), stream);
  cvt_bf16<<<1024, 256, 0, stream>>>(W_ih, Wih_bf, (long)G_DIM * D_IN / 4);
  cvt_bf16<<<1024, 256, 0, stream>>>(W_hh, Whh_bf, (long)G_DIM * H_DIM / 4);
  cvt_bf16<<<512, 256, 0, stream>>>(hxs, hbuf, (long)N_B * H_DIM / 4);   // hbuf[0] = bf16(h0)
  reset_kernel<<<128, 512, 0, stream>>>(masks, reset);

  for (int ck = 0; ck < NCHUNK; ++ck) {
    const float* xck = x + (size_t)ck * M_CHUNK * D_IN;
    cvt_bf16<<<2048, 256, 0, stream>>>(xck, xc_bf, (long)M_CHUNK * D_IN / 4);
    dim3 gg(G_DIM / 128, M_CHUNK / 128);   // (24, 32)
    gemm_xp<<<gg, 256, 0, stream>>>(xc_bf, Wih_bf, b_ih, xp_bf);

    rnn_chunk2<<<256, 256, 0, stream>>>(Whh_bf, xp_bf, masks, reset, b_hh,
                                        hxs, hbuf, y, hlast, bars + ck * 8, ck * CHUNK);
  }

  ln_kernel<<<T_STEPS * N_B, 256, 0, stream>>>(y, gamma, beta);
}

// Round 6
// 3250.097 us; speedup vs baseline: 2.6165x; 1.5951x over previous
//
#include <hip/hip_runtime.h>

// ---------------- problem constants ----------------
#define T_STEPS 128
#define N_B     512
#define D_IN    1024
#define H_DIM   1024
#define G_DIM   3072        // 3*H
#define CHUNK   8           // timesteps per xp-GEMM chunk / persistent launch
#define NCHUNK  16
#define M_CHUNK (CHUNK * N_B)   // 4096 rows per xp-GEMM chunk

typedef short          s8v  __attribute__((ext_vector_type(8)));   // 8 bf16 (4 VGPR)
typedef float          f4v  __attribute__((ext_vector_type(4)));
typedef unsigned short u4v  __attribute__((ext_vector_type(4)));

__device__ __forceinline__ unsigned short f2bf(float f) {
  union { float f; unsigned u; } v; v.f = f;
  unsigned r = v.u + 0x7FFFu + ((v.u >> 16) & 1u);   // RNE
  return (unsigned short)(r >> 16);
}
__device__ __forceinline__ float bf2f(unsigned short h) {
  union { unsigned u; float f; } v; v.u = ((unsigned)h) << 16;
  return v.f;
}
__device__ __forceinline__ void async16(const void* g, void* l) {
  __builtin_amdgcn_global_load_lds(
      (const __attribute__((address_space(1))) unsigned*)g,
      (__attribute__((address_space(3))) unsigned*)l, 16, 0, 0);
}
// sc0-coherent variant: bypass vL1, read the XCD's L2 (for cross-block h state)
__device__ __forceinline__ void async16_sc0(const void* g, void* l) {
  __builtin_amdgcn_global_load_lds(
      (const __attribute__((address_space(1))) unsigned*)g,
      (__attribute__((address_space(3))) unsigned*)l, 16, 0, 1);
}
__device__ __forceinline__ float sigmoidf_(float x) { return 1.f / (1.f + __expf(-x)); }
__device__ __forceinline__ float tanhf_(float x)    { return 1.f - 2.f / (1.f + __expf(2.f * x)); }

// ---------------- f32 -> bf16 conversion (vectorized, grid-stride) ----------------
__global__ void cvt_bf16(const float* __restrict__ in, unsigned short* __restrict__ out, long n4) {
  long i = (long)blockIdx.x * blockDim.x + threadIdx.x;
  long stride = (long)gridDim.x * blockDim.x;
  for (; i < n4; i += stride) {
    f4v v = *(const f4v*)(in + i * 4);
    u4v o;
    #pragma unroll
    for (int e = 0; e < 4; ++e) o[e] = f2bf(v[e]);
    *(u4v*)(out + i * 4) = o;
  }
}

// ---------------- reset[t] = (t==0) || any(m[t,:]==1.0) ----------------
__global__ void reset_kernel(const float* __restrict__ masks, int* __restrict__ reset) {
  const int t = blockIdx.x;
  __shared__ int flag;
  if (threadIdx.x == 0) flag = (t == 0) ? 1 : 0;
  __syncthreads();
  if (t > 0 && masks[(size_t)t * N_B + threadIdx.x] == 1.0f) flag = 1;  // benign same-value race
  __syncthreads();
  if (threadIdx.x == 0) reset[t] = flag;
}

// ---------------- xp chunk GEMM: C[m][g] = sum_k A[m][k]*B[g][k] + bias[g] ----------------
__global__ __launch_bounds__(256) void gemm_xp(const unsigned short* __restrict__ A,
                                               const unsigned short* __restrict__ B,
                                               const float* __restrict__ bias,
                                               unsigned short* __restrict__ C) {
  const int m0 = blockIdx.y * 128, g0 = blockIdx.x * 128;
  const int tid = threadIdx.x, wv = tid >> 6, l = tid & 63;
  const int l15 = l & 15, l4 = l >> 4;
  const int wr = wv >> 1, wc = wv & 1;
  __shared__ unsigned short As[128 * 64], Bs[128 * 64];

  f4v zero4 = {0.f, 0.f, 0.f, 0.f};
  f4v acc[4][4];
  #pragma unroll
  for (int i = 0; i < 4; ++i)
    #pragma unroll
    for (int j = 0; j < 4; ++j) acc[i][j] = zero4;

  const int srow = l >> 3;
  const int selem = (l & 7) * 8;

  for (int kt = 0; kt < 1024; kt += 64) {
    #pragma unroll
    for (int cc = 0; cc < 4; ++cc) {
      int s = wv * 4 + cc;
      int row = s * 8 + srow;
      async16(A + (size_t)(m0 + row) * 1024 + kt + selem, &As[s * 512]);
      async16(B + (size_t)(g0 + row) * 1024 + kt + selem, &Bs[s * 512]);
    }
    __syncthreads();
    #pragma unroll
    for (int ks = 0; ks < 2; ++ks) {
      s8v a[4], b[4];
      #pragma unroll
      for (int i = 0; i < 4; ++i) {
        a[i] = *(const s8v*)&As[(wr * 64 + i * 16 + l15) * 64 + ks * 32 + l4 * 8];
        b[i] = *(const s8v*)&Bs[(wc * 64 + i * 16 + l15) * 64 + ks * 32 + l4 * 8];
      }
      #pragma unroll
      for (int i = 0; i < 4; ++i)
        #pragma unroll
        for (int j = 0; j < 4; ++j)
          acc[i][j] = __builtin_amdgcn_mfma_f32_16x16x32_bf16(a[i], b[j], acc[i][j], 0, 0, 0);
    }
    __syncthreads();
  }
  #pragma unroll
  for (int j = 0; j < 4; ++j) {
    int gcol = g0 + wc * 64 + j * 16 + l15;
    float bv = bias[gcol];
    #pragma unroll
    for (int i = 0; i < 4; ++i) {
      int mrow = m0 + wr * 64 + i * 16 + l4 * 4;
      #pragma unroll
      for (int r = 0; r < 4; ++r)
        C[(size_t)(mrow + r) * G_DIM + gcol] = f2bf(acc[i][j][r] + bv);
    }
  }
}

// ---------------- persistent GRU recurrence (no fences, L2 stays hot) ----------------
// 256 blocks: g = bid&7 (n-group of 64 rows -> XCD g), c = bid>>3 (32 j-chunks of 32 cols).
// Coherence model (replaces round-5's agent fence, which invalidated L2 every step):
//   - vL1 is write-through; __syncthreads drains vmcnt(0) -> h stores are in the XCD's L2
//     before tid0's (relaxed) flag increment.
//   - h staging reads use sc0 (aux=1) global_load_lds -> bypass vL1, read fresh L2.
//   - barrier atomics RELAXED at agent scope: coherent flag access WITHOUT buffer_inv/wbl2.
//   - W_hh/xp staging stays normally cached -> W slice stays L2-resident across all steps.
__global__ __launch_bounds__(256) void rnn_chunk2(
    const unsigned short* __restrict__ Whh,   // [3072][1024] bf16
    const unsigned short* __restrict__ xp,    // [CHUNK][512][3072] bf16 (+b_ih)
    const float* __restrict__ masks,          // [T*N]
    const int* __restrict__ reset,            // [T]
    const float* __restrict__ bhh,            // [3072]
    const float* __restrict__ hxs,            // [512][1024] initial h (f32)
    unsigned short* hbuf,                     // [2][512][1024] bf16 state
    float* y,                                 // [T*N][1024] (d_out)
    float* hlast,                             // [512][1024]  (d_out tail)
    unsigned* bar,                            // [8] group counters (this launch's slot)
    int t0) {
  const int bid = blockIdx.x;
  const int g = bid & 7, c = bid >> 3;
  const int n0 = g * 64, j0 = c * 32;
  const int tid = threadIdx.x, w = tid >> 6, l = tid & 63;
  const int l15 = l & 15, l4 = l >> 4;
  const int wn = w & 1, wj = w >> 1;          // wave -> (n-half of 32, j-half of 16)
  const size_t NH = (size_t)N_B * H_DIM;

  __shared__ unsigned short Hs[2][64 * 128];  // 2 x 16 KB (h slab, swizzled)
  __shared__ unsigned short Ws[2][96 * 128];  // 2 x 24 KB (W slab, swizzled)

  const int lrow4 = l >> 4;                   // staging: lane -> row-within-4
  const int lcb = (l & 15) * 16;              // staging: lane -> 16B col slot
  const int swz_rd = (l15 & 7) << 4;          // read-side row-XOR

  const int jj = j0 + wj * 16 + l15;
  const float br = bhh[jj];
  const float bz = bhh[H_DIM + jj];
  const float bn = bhh[2 * H_DIM + jj];

  // h_prev in registers, layout == acc layout: (i,r) -> n = n0+wn*32+i*16+l4*4+r
  float hreg[2][4];
  {
    const float* hsrc = (t0 == 0) ? hxs : (y + (size_t)(t0 - 1) * NH);
    #pragma unroll
    for (int i = 0; i < 2; ++i)
      #pragma unroll
      for (int r = 0; r < 4; ++r)
        hreg[i][r] = hsrc[(size_t)(n0 + wn * 32 + i * 16 + l4 * 4 + r) * H_DIM + jj];
  }

  f4v zero4 = {0.f, 0.f, 0.f, 0.f};
  s8v zer8 = {0, 0, 0, 0, 0, 0, 0, 0};

  for (int ls = 0; ls < CHUNK; ++ls) {
    const int t = t0 + ls;
    const unsigned short* hread = hbuf + (size_t)(t & 1) * NH;
    unsigned short* hwrite = hbuf + (size_t)((t & 1) ^ 1) * NH;
    const int rst = reset[t];

    bool zo[2];
    #pragma unroll
    for (int i = 0; i < 2; ++i) {
      float mv = masks[(size_t)t * N_B + n0 + wn * 32 + i * 16 + l15];
      zo[i] = rst && (mv == 0.0f);
    }

    f4v acc[2][3];
    #pragma unroll
    for (int i = 0; i < 2; ++i)
      #pragma unroll
      for (int g3 = 0; g3 < 3; ++g3) acc[i][g3] = zero4;

    // ---- staging (wave-uniform LDS dest, per-lane pre-swizzled global src) ----
    auto stageH = [&](int buf, int kt) {
      #pragma unroll
      for (int q = 0; q < 4; ++q) {
        int rb = w * 16 + q * 4;
        int row = rb + lrow4;                                   // 0..63
        int cb = lcb ^ ((row & 7) << 4);                        // byte in 256B row
        async16_sc0(hread + (size_t)(n0 + row) * H_DIM + kt * 128 + (cb >> 1),
                    &Hs[buf][rb * 128]);                        // sc0: fresh from L2
      }
    };
    auto stageW = [&](int buf, int kt) {
      #pragma unroll
      for (int q = 0; q < 6; ++q) {
        int rb = w * 24 + q * 4;
        int row = rb + lrow4;                                   // 0..95
        int gate = row >> 5, jjl = row & 31;
        int cb = lcb ^ ((row & 7) << 4);
        async16(Whh + ((size_t)gate * H_DIM + j0 + jjl) * H_DIM + kt * 128 + (cb >> 1),
                &Ws[buf][rb * 128]);
      }
    };

    stageH(0, 0);
    stageW(0, 0);
    __syncthreads();

    for (int kt = 0; kt < 8; ++kt) {
      const int cur = kt & 1;
      if (kt < 7) { stageH(cur ^ 1, kt + 1); stageW(cur ^ 1, kt + 1); }  // prefetch overlaps MFMA
      const char* hb = (const char*)&Hs[cur][0];
      const char* wb = (const char*)&Ws[cur][0];
      #pragma unroll
      for (int ks = 0; ks < 4; ++ks) {
        const int kbb = (ks * 64 + l4 * 16) ^ swz_rd;
        s8v a[2], b[3];
        #pragma unroll
        for (int i = 0; i < 2; ++i) {
          a[i] = *(const s8v*)(hb + (wn * 32 + i * 16 + l15) * 256 + kbb);
          if (zo[i]) a[i] = zer8;
        }
        #pragma unroll
        for (int g3 = 0; g3 < 3; ++g3)
          b[g3] = *(const s8v*)(wb + (g3 * 32 + wj * 16 + l15) * 256 + kbb);
        #pragma unroll
        for (int i = 0; i < 2; ++i)
          #pragma unroll
          for (int g3 = 0; g3 < 3; ++g3)
            acc[i][g3] = __builtin_amdgcn_mfma_f32_16x16x32_bf16(a[i], b[g3], acc[i][g3], 0, 0, 0);
      }
      __syncthreads();
    }

    // ---- gates fully in-register ----
    const unsigned short* xpt = xp + (size_t)ls * N_B * G_DIM;
    #pragma unroll
    for (int i = 0; i < 2; ++i) {
      #pragma unroll
      for (int r = 0; r < 4; ++r) {
        const int n = n0 + wn * 32 + i * 16 + l4 * 4 + r;
        const float m = masks[(size_t)t * N_B + n];
        float hprev = hreg[i][r];
        if (rst && m == 0.0f) hprev = 0.0f;
        const float hr = acc[i][0][r] + br;
        const float hz = acc[i][1][r] + bz;
        const float hn = acc[i][2][r] + bn;
        const size_t xo = (size_t)n * G_DIM + jj;
        const float xr = bf2f(xpt[xo]);
        const float xz = bf2f(xpt[xo + H_DIM]);
        const float xn = bf2f(xpt[xo + 2 * H_DIM]);
        const float rg = sigmoidf_(xr + hr);
        const float zg = sigmoidf_(xz + hz);
        const float ng = tanhf_(xn + rg * hn);
        const float hnew = (1.f - zg) * ng + zg * hprev;
        hreg[i][r] = hnew;
        const size_t gidx = (size_t)n * H_DIM + jj;
        y[(size_t)t * NH + gidx] = hnew;
        hwrite[gidx] = f2bf(hnew);
        if (t == T_STEPS - 1) hlast[gidx] = hnew;
      }
    }

    // ---- group barrier (32 blocks), NO cache-invalidating fences ----
    // __syncthreads drains vmcnt(0) per wave before s_barrier -> all h stores are in L2
    // (vL1 write-through) before tid0's relaxed increment becomes visible.
    __syncthreads();
    if (tid == 0) {
      __hip_atomic_fetch_add(&bar[g], 1u, __ATOMIC_RELAXED, __HIP_MEMORY_SCOPE_AGENT);
      const unsigned tgt = 32u * (unsigned)(ls + 1);
      while (__hip_atomic_load(&bar[g], __ATOMIC_RELAXED, __HIP_MEMORY_SCOPE_AGENT) < tgt)
        __builtin_amdgcn_s_sleep(2);
    }
    __syncthreads();
  }
}

// ---------------- final LayerNorm over y rows (in place) ----------------
__global__ __launch_bounds__(256) void ln_kernel(float* __restrict__ y,
                                                 const float* __restrict__ gamma,
                                                 const float* __restrict__ beta) {
  const size_t row = blockIdx.x;
  float* p = y + row * (size_t)H_DIM;
  const int tid = threadIdx.x;
  f4v v = *(const f4v*)(p + tid * 4);
  float s = v[0] + v[1] + v[2] + v[3];
  float q = v[0] * v[0] + v[1] * v[1] + v[2] * v[2] + v[3] * v[3];
  #pragma unroll
  for (int off = 32; off > 0; off >>= 1) {
    s += __shfl_down(s, off);
    q += __shfl_down(q, off);
  }
  __shared__ float sb[8];
  const int wid = tid >> 6, lid = tid & 63;
  if (lid == 0) { sb[wid] = s; sb[4 + wid] = q; }
  __syncthreads();
  float S = sb[0] + sb[1] + sb[2] + sb[3];
  float Q = sb[4] + sb[5] + sb[6] + sb[7];
  float mean = S * (1.f / H_DIM);
  float var = Q * (1.f / H_DIM) - mean * mean;
  float inv = rsqrtf(var + 1e-5f);
  f4v g4 = *(const f4v*)(gamma + tid * 4);
  f4v b4 = *(const f4v*)(beta + tid * 4);
  f4v o;
  #pragma unroll
  for (int e = 0; e < 4; ++e) o[e] = (v[e] - mean) * inv * g4[e] + b4[e];
  *(f4v*)(p + tid * 4) = o;
}

// ---------------- host ----------------
extern "C" void kernel_launch(void* const* d_in, const int* in_sizes, int n_in,
                              void* d_out, int out_size, void* d_ws, size_t ws_size,
                              hipStream_t stream) {
  const float* x     = (const float*)d_in[0];
  const float* hxs   = (const float*)d_in[1];
  const float* masks = (const float*)d_in[2];
  const float* W_ih  = (const float*)d_in[3];
  const float* W_hh  = (const float*)d_in[4];
  const float* b_ih  = (const float*)d_in[5];
  const float* b_hh  = (const float*)d_in[6];
  const float* gamma = (const float*)d_in[7];
  const float* beta  = (const float*)d_in[8];
  float* y = (float*)d_out;                                 // [65536][1024]
  float* hlast = y + (size_t)T_STEPS * N_B * H_DIM;         // [512][1024]

  char* ws = (char*)d_ws;
  unsigned short* Wih_bf = (unsigned short*)ws;  ws += (size_t)G_DIM * D_IN * 2;       // 6.3 MB
  unsigned short* Whh_bf = (unsigned short*)ws;  ws += (size_t)G_DIM * H_DIM * 2;      // 6.3 MB
  unsigned short* xc_bf  = (unsigned short*)ws;  ws += (size_t)M_CHUNK * D_IN * 2;     // 8.4 MB
  unsigned short* xp_bf  = (unsigned short*)ws;  ws += (size_t)M_CHUNK * G_DIM * 2;    // 25.2 MB
  unsigned short* hbuf   = (unsigned short*)ws;  ws += (size_t)2 * N_B * H_DIM * 2;    // 2.1 MB
  int* reset             = (int*)ws;             ws += 512;
  unsigned* bars         = (unsigned*)ws;        ws += NCHUNK * 8 * sizeof(unsigned);

  hipMemsetAsync(bars, 0, NCHUNK * 8 * sizeof(unsigned), stream);
  cvt_bf16<<<1024, 256, 0, stream>>>(W_ih, Wih_bf, (long)G_DIM * D_IN / 4);
  cvt_bf16<<<1024, 256, 0, stream>>>(W_hh, Whh_bf, (long)G_DIM * H_DIM / 4);
  cvt_bf16<<<512, 256, 0, stream>>>(hxs, hbuf, (long)N_B * H_DIM / 4);   // hbuf[0] = bf16(h0)
  reset_kernel<<<128, 512, 0, stream>>>(masks, reset);

  for (int ck = 0; ck < NCHUNK; ++ck) {
    const float* xck = x + (size_t)ck * M_CHUNK * D_IN;
    cvt_bf16<<<2048, 256, 0, stream>>>(xck, xc_bf, (long)M_CHUNK * D_IN / 4);
    dim3 gg(G_DIM / 128, M_CHUNK / 128);   // (24, 32)
    gemm_xp<<<gg, 256, 0, stream>>>(xc_bf, Wih_bf, b_ih, xp_bf);

    rnn_chunk2<<<256, 256, 0, stream>>>(Whh_bf, xp_bf, masks, reset, b_hh,
                                        hxs, hbuf, y, hlast, bars + ck * 8, ck * CHUNK);
  }

  ln_kernel<<<T_STEPS * N_B, 256, 0, stream>>>(y, gamma, beta);
}